// Round 3
// baseline (422.523 us; speedup 1.0000x reference)
//
#include <hip/hip_runtime.h>
#include <math.h>

#define HH 1024
#define VV 50000
#define NB2 1250           // K2 blocks: 5000 waves, exactly 10 rows/wave

// butterfly reduce over the 64-lane wave: all lanes end with the total
__device__ __forceinline__ float wredsum(float v) {
#pragma unroll
    for (int o = 32; o > 0; o >>= 1) v += __shfl_xor(v, o);
    return v;
}

// ---------------------------------------------------------------------------
// K1: LSTM cell. block = hidden index j (1024 blocks), wave = gate g (4 waves).
// Two independent accumulator chains (W_ih, W_hh) to double FMA ILP.
// ---------------------------------------------------------------------------
__global__ __launch_bounds__(256, 4) void lstm_kernel(
    const int* __restrict__ tok, const float* __restrict__ emb,
    const float* __restrict__ h0, const float* __restrict__ c0,
    const float* __restrict__ W_ih, const float* __restrict__ W_hh,
    const float* __restrict__ b_ih, const float* __restrict__ b_hh,
    float* __restrict__ out)  // d_out: [V logits][H h_new][H c_new]
{
    __shared__ float sg[4];
    const int g    = threadIdx.x >> 6;               // gate = wave id
    const int lane = threadIdx.x & 63;
    const int j    = blockIdx.x;                     // 0..1023
    const int t    = tok[0];                         // int64 low word
    const float* e = emb + (size_t)t * HH;

    const float* wi = W_ih + (size_t)(g * HH + j) * HH;
    const float* wh = W_hh + (size_t)(g * HH + j) * HH;

    float acc0 = 0.f, acc1 = 0.f;
#pragma unroll
    for (int k = 0; k < 4; ++k) {
        const int idx = k * 256 + lane * 4;
        const float4 a  = *(const float4*)(wi + idx);
        const float4 b  = *(const float4*)(wh + idx);
        const float4 ev = *(const float4*)(e  + idx);
        const float4 hv = *(const float4*)(h0 + idx);
        acc0 += a.x * ev.x + a.y * ev.y + a.z * ev.z + a.w * ev.w;
        acc1 += b.x * hv.x + b.y * hv.y + b.z * hv.z + b.w * hv.w;
    }
    const float acc = wredsum(acc0 + acc1);
    if (lane == 0) sg[g] = acc + b_ih[g * HH + j] + b_hh[g * HH + j];
    __syncthreads();

    if (threadIdx.x == 0) {
        const float si = 1.f / (1.f + expf(-sg[0]));
        const float sf = 1.f / (1.f + expf(-sg[1]));
        const float gg = tanhf(sg[2]);
        const float so = 1.f / (1.f + expf(-sg[3]));
        const float cn = sf * c0[j] + si * gg;
        const float hn = so * tanhf(cn);
        out[VV + j]      = hn;
        out[VV + HH + j] = cn;
    }
}

// ---------------------------------------------------------------------------
// K2: logits[r] = out_W[r]·h + out_b[r]. 10 rows/wave, 10 per-lane
// accumulators — NO cross-lane ops inside the streaming loop (keeps the
// VMEM queue full). All wredsums + online-softmax done once at the end.
// ---------------------------------------------------------------------------
__global__ __launch_bounds__(256, 4) void logits_kernel(
    const float* __restrict__ out_W, const float* __restrict__ out_b,
    const float* __restrict__ h,      // = d_out + V (written by K1)
    float* __restrict__ logits,       // = d_out
    float2* __restrict__ part)        // [NB2] (m_b, s_b)
{
    __shared__ float2 sp[4];
    const int wid  = threadIdx.x >> 6;
    const int lane = threadIdx.x & 63;
    const int gw   = blockIdx.x * 4 + wid;           // 0..4999

    float4 hv[4];
#pragma unroll
    for (int k = 0; k < 4; ++k)
        hv[k] = *(const float4*)(h + k * 256 + lane * 4);

    float acc[10];
#pragma unroll
    for (int i = 0; i < 10; ++i) acc[i] = 0.f;

#pragma unroll
    for (int i = 0; i < 10; ++i) {
        const float* w = out_W + (size_t)(gw + i * 5000) * HH;
#pragma unroll
        for (int k = 0; k < 4; ++k) {
            const float4 x = *(const float4*)(w + k * 256 + lane * 4);
            acc[i] += x.x * hv[k].x + x.y * hv[k].y + x.z * hv[k].z + x.w * hv[k].w;
        }
    }

    float v[10];
#pragma unroll
    for (int i = 0; i < 10; ++i)
        v[i] = wredsum(acc[i]) + out_b[gw + i * 5000];   // uniform across lanes

    if (lane == 0) {
#pragma unroll
        for (int i = 0; i < 10; ++i) logits[gw + i * 5000] = v[i];
    }

    // online-softmax partial for this wave (uniform, no divergence)
    float m = v[0];
#pragma unroll
    for (int i = 1; i < 10; ++i) m = fmaxf(m, v[i]);
    float s = 0.f;
#pragma unroll
    for (int i = 0; i < 10; ++i) s += expf(v[i] - m);

    if (lane == 0) sp[wid] = make_float2(m, s);
    __syncthreads();
    if (threadIdx.x == 0) {
        float2 p = sp[0];
#pragma unroll
        for (int w = 1; w < 4; ++w) {
            const float2 q = sp[w];
            const float nm = fmaxf(p.x, q.x);
            p.y = p.y * expf(p.x - nm) + q.y * expf(q.x - nm);
            p.x = nm;
        }
        part[blockIdx.x] = p;
    }
}

// ---------------------------------------------------------------------------
// K3: one block of 256 — merge 1250 (m, s) partials -> logZ = M + log(S)
// ---------------------------------------------------------------------------
__global__ __launch_bounds__(256) void logz_kernel(
    const float2* __restrict__ part, int nblk, float* __restrict__ logz)
{
    __shared__ float2 red[256];
    float m = -INFINITY, s = 0.f;
    for (int i = threadIdx.x; i < nblk; i += 256) {
        const float2 q = part[i];
        const float nm = fmaxf(m, q.x);
        s = s * expf(m - nm) + q.y * expf(q.x - nm);
        m = nm;
    }
    red[threadIdx.x] = make_float2(m, s);
    __syncthreads();
    for (int st = 128; st > 0; st >>= 1) {
        if (threadIdx.x < st) {
            float2 p = red[threadIdx.x], q = red[threadIdx.x + st];
            const float nm = fmaxf(p.x, q.x);
            p.y = p.y * expf(p.x - nm) + q.y * expf(q.x - nm);
            p.x = nm;
            red[threadIdx.x] = p;
        }
        __syncthreads();
    }
    if (threadIdx.x == 0) *logz = red[0].x + logf(red[0].y);
}

// ---------------------------------------------------------------------------
// K4: logits[v] -= logZ  (in place in d_out), float4 vectorized.
// VV = 50000 = 12500 float4s -> 49 blocks of 256.
// ---------------------------------------------------------------------------
__global__ __launch_bounds__(256) void sub_kernel(
    float* __restrict__ logits, const float* __restrict__ logz)
{
    const float lz = *logz;
    const int i = blockIdx.x * 256 + threadIdx.x;    // float4 index
    if (i < VV / 4) {
        float4 x = ((float4*)logits)[i];
        x.x -= lz; x.y -= lz; x.z -= lz; x.w -= lz;
        ((float4*)logits)[i] = x;
    }
}

extern "C" void kernel_launch(void* const* d_in, const int* in_sizes, int n_in,
                              void* d_out, int out_size, void* d_ws, size_t ws_size,
                              hipStream_t stream) {
    const int*   tok   = (const int*)  d_in[0];
    const float* h0    = (const float*)d_in[1];
    const float* c0    = (const float*)d_in[2];
    // d_in[3] encoder_outputs — dead code, never read
    const float* emb   = (const float*)d_in[4];
    // d_in[5..8] attn_W, attn_b, comb_W, comb_b — dead code, never read
    const float* W_ih  = (const float*)d_in[9];
    const float* W_hh  = (const float*)d_in[10];
    const float* b_ih  = (const float*)d_in[11];
    const float* b_hh  = (const float*)d_in[12];
    const float* out_W = (const float*)d_in[13];
    const float* out_b = (const float*)d_in[14];

    float* out = (float*)d_out;

    float2* part = (float2*)d_ws;     // [NB2] (m_b, s_b) partials
    float*  logz = (float*)(part + NB2);

    lstm_kernel<<<1024, 256, 0, stream>>>(tok, emb, h0, c0, W_ih, W_hh, b_ih, b_hh, out);
    logits_kernel<<<NB2, 256, 0, stream>>>(out_W, out_b, out + VV, out, part);
    logz_kernel<<<1, 256, 0, stream>>>(part, NB2, logz);
    sub_kernel<<<(VV / 4 + 255) / 256, 256, 0, stream>>>(out, logz);
}